// Round 1
// baseline (149082.336 us; speedup 1.0000x reference)
//
#include <hip/hip_runtime.h>

typedef unsigned int u32;
typedef unsigned long long u64;
typedef float f32x4 __attribute__((ext_vector_type(4)));

// np-bit-exact Leaky update: m' = f32(f32(f32(0.95f*m) + cur) - reset)
// reset from PREVIOUS mem; (mem-1>0) === (mem>1) exactly in f32 (Sterbenz).
__device__ __forceinline__ float leaky(float m, float cur) {
  float r = (m > 1.0f) ? 1.0f : 0.0f;
  return __fsub_rn(__fadd_rn(__fmul_rn(0.95f, m), cur), r);
}

// ---------------------------------------------------------------------------
// Phase A: cur1 (exact FMA chain, d ascending) + layer-1 sim; emit per-step
// spike bitmasks to global in [t][kw][sample] layout (word kw covers
// k in [kw*32, kw*32+32), bit i <-> k = kw*32+i — same bit order as before).
// Wave = 1 sample, block = 4 waves.
// ---------------------------------------------------------------------------
__global__ __launch_bounds__(256) void k_spk1(
    const float* __restrict__ x, const float* __restrict__ W1,
    const float* __restrict__ b1, u32* __restrict__ masks,
    int s0, int Sc) {
  __shared__ float w1s[8 * 1024];
  const int tid = threadIdx.x, lane = tid & 63, w = tid >> 6;
  const int sl = blockIdx.x * 4 + w;
  const size_t s = (size_t)s0 + sl;

  float c1[16];
#pragma unroll
  for (int j = 0; j < 16; ++j) c1[j] = 0.0f;
#pragma unroll 1
  for (int ch = 0; ch < 8; ++ch) {
    __syncthreads();
#pragma unroll
    for (int it = 0; it < 8; ++it) {
      int v = tid + it * 256;
      *(f32x4*)(w1s + v * 4) =
          *(const f32x4*)(W1 + (size_t)(ch * 8 + (v >> 8)) * 1024 + (v & 255) * 4);
    }
    __syncthreads();
#pragma unroll 1
    for (int dl = 0; dl < 8; ++dl) {
      float xv = x[s * 64 + ch * 8 + dl];
#pragma unroll
      for (int j = 0; j < 16; ++j)
        c1[j] = fmaf(xv, w1s[dl * 1024 + j * 64 + lane], c1[j]);
    }
  }
#pragma unroll
  for (int j = 0; j < 16; ++j) c1[j] = __fadd_rn(c1[j], b1[j * 64 + lane]);

  float m1[16];
#pragma unroll
  for (int j = 0; j < 16; ++j) m1[j] = 0.0f;

#pragma unroll 1
  for (int t = 0; t < 25; ++t) {
#pragma unroll
    for (int j = 0; j < 16; ++j) {
      m1[j] = leaky(m1[j], c1[j]);
      u64 ball = __ballot(m1[j] > 1.0f);
      if (lane == 0) {
        masks[((size_t)t * 32 + 2 * j) * Sc + sl] = (u32)ball;
        masks[((size_t)t * 32 + 2 * j + 1) * Sc + sl] = (u32)(ball >> 32);
      }
    }
  }
}

// ---------------------------------------------------------------------------
// Phase B: cur2 for 16 samples x 1 step per wave. k-outer shared row loads:
// each W2 row loaded ONCE per wave (2x dwordx4, n = lane*4 + q*256, perfectly
// coalesced 1KB/instr), gated add per sample via wave-uniform scalar branch
// (s_and sets SCC -> s_cbranch: 2 SALU per (item,k)). Ascending-k f32 add
// chain per n is bit-identical to the BLAS fma chain (fma(0,w,c)=c exact).
// Double-buffered row regs hide L1/L2 latency.
// ---------------------------------------------------------------------------
__global__ __launch_bounds__(256) void k_cur2(
    const float* __restrict__ W2, const float* __restrict__ b2,
    const u32* __restrict__ masks, float* __restrict__ cur2, int Sc) {
  const int tid = threadIdx.x, lane = tid & 63, w = tid >> 6;
  const int task = blockIdx.x * 4 + w;     // < Sc*25/16
  const int grp = task / 25, t = task - grp * 25;
  const int sl0 = grp * 16;
  const int lq = lane * 4;

  f32x4 a[16][2];
#pragma unroll
  for (int g = 0; g < 16; ++g) { a[g][0] = 0.0f; a[g][1] = 0.0f; }

  const u32* mrow = masks + (size_t)t * 32 * Sc + sl0;

  f32x4 rA0 = *(const f32x4*)(W2 + lq);
  f32x4 rA1 = *(const f32x4*)(W2 + 256 + lq);

#pragma unroll 1
  for (int kw = 0; kw < 32; ++kw) {
    const u32* mp = mrow + (size_t)kw * Sc;
    u32 wd[16];
#pragma unroll
    for (int g = 0; g < 16; ++g) wd[g] = __builtin_amdgcn_readfirstlane(mp[g]);
#pragma unroll 1
    for (int k2 = 0; k2 < 16; ++k2) {
      const int k = kw * 32 + k2 * 2;
      const int kk = k2 * 2;
      const u32 bit0 = 1u << kk;
      const u32 bit1 = 2u << kk;
      const float* pB = W2 + (size_t)(k + 1) * 512 + lq;
      f32x4 rB0 = *(const f32x4*)(pB);
      f32x4 rB1 = *(const f32x4*)(pB + 256);
#pragma unroll
      for (int g = 0; g < 16; ++g)
        if (wd[g] & bit0) { a[g][0] += rA0; a[g][1] += rA1; }
      const int kn = (k + 2 < 1024) ? k + 2 : 1023;   // harmless clamp at tail
      const float* pA = W2 + (size_t)kn * 512 + lq;
      rA0 = *(const f32x4*)(pA);
      rA1 = *(const f32x4*)(pA + 256);
#pragma unroll
      for (int g = 0; g < 16; ++g)
        if (wd[g] & bit1) { a[g][0] += rB0; a[g][1] += rB1; }
    }
  }

  const f32x4 bv0 = *(const f32x4*)(b2 + lq);
  const f32x4 bv1 = *(const f32x4*)(b2 + 256 + lq);
#pragma unroll
  for (int g = 0; g < 16; ++g) {
    f32x4 o0 = a[g][0] + bv0;   // plain + is RN (no fast-math): exact +b2
    f32x4 o1 = a[g][1] + bv1;
    float* op = cur2 + ((size_t)(sl0 + g) * 25 + t) * 512 + lq;
    *(f32x4*)(op) = o0;
    *(f32x4*)(op + 256) = o1;
  }
}

// ---------------------------------------------------------------------------
// Phase C: layers 2-3 recurrence off stored cur2 (exact f32 round-trip).
// Wave = 1 sample; n = j*64+lane mapping so ballots give n-ordered words;
// lane-0 ascending-n ffs chain identical to the verified kernel, with a
// 1-deep LDS-load pipeline. Mean+sigmoid in f64.
// ---------------------------------------------------------------------------
__global__ __launch_bounds__(256) void k_tail(
    const float* __restrict__ cur2, const float* __restrict__ W3,
    const float* __restrict__ b3, float* __restrict__ out, int s0, int Sc) {
  __shared__ float w3s[512];
  const int tid = threadIdx.x, lane = tid & 63, w = tid >> 6;
  const int sl = blockIdx.x * 4 + w;
  for (int i = tid; i < 512; i += 256) w3s[i] = W3[i];
  __syncthreads();

  float m2[8];
#pragma unroll
  for (int j = 0; j < 8; ++j) m2[j] = 0.0f;
  float m3 = 0.0f;
  double s3 = 0.0;
  const float b3v = b3[0];
  const float* cp = cur2 + (size_t)sl * 25 * 512;

#pragma unroll 1
  for (int t = 0; t < 25; ++t) {
    u64 s2b[8];
#pragma unroll
    for (int j = 0; j < 8; ++j) {
      float cur = cp[t * 512 + j * 64 + lane];
      m2[j] = leaky(m2[j], cur);
      s2b[j] = __ballot(m2[j] > 1.0f);
    }
    if (lane == 0) {
      float c3 = 0.0f;
#pragma unroll 1
      for (int j = 0; j < 8; ++j) {
        u64 mm = s2b[j];
        const int nb = j * 64;
        if (mm) {
          int nn = __ffsll(mm) - 1;
          mm &= mm - 1;
          float wv = w3s[nb + nn];
          while (mm) {
            int n2 = __ffsll(mm) - 1;
            mm &= mm - 1;
            float wn = w3s[nb + n2];   // next load issued before dependent add
            c3 = __fadd_rn(c3, wv);
            wv = wn;
          }
          c3 = __fadd_rn(c3, wv);
        }
      }
      c3 = __fadd_rn(c3, b3v);
      m3 = leaky(m3, c3);
      s3 += (double)m3;
    }
  }
  if (lane == 0) {
    double z = s3 / 25.0;
    out[s0 + sl] = (float)(1.0 / (1.0 + exp(-z)));
  }
}

// ---------------------------------------------------------------------------
// Fallback: previous verified single-kernel path (used if workspace too small)
// ---------------------------------------------------------------------------
__global__ __launch_bounds__(256) void k_snn(
    const float* __restrict__ x, const float* __restrict__ W1,
    const float* __restrict__ b1, const float* __restrict__ W2,
    const float* __restrict__ b2, const float* __restrict__ W3,
    const float* __restrict__ b3, float* __restrict__ out) {
  __shared__ float w1s[8 * 1024];
  __shared__ float w3s[512];
  __shared__ u32 spkm[4][32];
  const int tid = threadIdx.x, lane = tid & 63, w = tid >> 6;
  const size_t s = (size_t)blockIdx.x * 4 + w;

  for (int i = tid; i < 512; i += 256) w3s[i] = W3[i];

  float c1[16];
#pragma unroll
  for (int j = 0; j < 16; ++j) c1[j] = 0.0f;
#pragma unroll 1
  for (int ch = 0; ch < 8; ++ch) {
    __syncthreads();
#pragma unroll
    for (int it = 0; it < 8; ++it) {
      int v = tid + it * 256;
      *(f32x4*)(w1s + v * 4) =
          *(const f32x4*)(W1 + (size_t)(ch * 8 + (v >> 8)) * 1024 + (v & 255) * 4);
    }
    __syncthreads();
#pragma unroll 1
    for (int dl = 0; dl < 8; ++dl) {
      float xv = x[s * 64 + ch * 8 + dl];
#pragma unroll
      for (int j = 0; j < 16; ++j)
        c1[j] = fmaf(xv, w1s[dl * 1024 + j * 64 + lane], c1[j]);
    }
  }
#pragma unroll
  for (int j = 0; j < 16; ++j) c1[j] = __fadd_rn(c1[j], b1[j * 64 + lane]);

  float m1[16];
#pragma unroll
  for (int j = 0; j < 16; ++j) m1[j] = 0.0f;
  float m2[8];
#pragma unroll
  for (int j = 0; j < 8; ++j) m2[j] = 0.0f;
  float b2l[8];
#pragma unroll
  for (int j = 0; j < 8; ++j) b2l[j] = b2[j * 64 + lane];
  const float b3v = b3[0];
  float m3 = 0.0f;
  double s3 = 0.0;

#pragma unroll 1
  for (int t = 0; t < 25; ++t) {
#pragma unroll
    for (int j = 0; j < 16; ++j) {
      m1[j] = leaky(m1[j], c1[j]);
      u64 ball = __ballot(m1[j] > 1.0f);
      if (lane == 0) {
        spkm[w][2 * j]     = (u32)ball;
        spkm[w][2 * j + 1] = (u32)(ball >> 32);
      }
    }
    __syncthreads();

    float c2[8];
#pragma unroll
    for (int j = 0; j < 8; ++j) c2[j] = 0.0f;
#pragma unroll 1
    for (int kw = 0; kw < 32; ++kw) {
      u32 mask = spkm[w][kw];
      int kbase = kw * 32;
      while (mask) {
        int kk = __ffs(mask) - 1;
        mask &= mask - 1;
        const float* wr = W2 + (size_t)(kbase + kk) * 512;
#pragma unroll
        for (int j = 0; j < 8; ++j)
          c2[j] = __fadd_rn(c2[j], wr[j * 64 + lane]);
      }
    }
    u64 s2b[8];
#pragma unroll
    for (int j = 0; j < 8; ++j) {
      float cur = __fadd_rn(c2[j], b2l[j]);
      m2[j] = leaky(m2[j], cur);
      s2b[j] = __ballot(m2[j] > 1.0f);
    }

    if (lane == 0) {
      float c3 = 0.0f;
#pragma unroll 1
      for (int j = 0; j < 8; ++j) {
        u64 mm = s2b[j];
        int nb = j * 64;
        while (mm) {
          int nn = __ffsll(mm) - 1;
          mm &= mm - 1;
          c3 = __fadd_rn(c3, w3s[nb + nn]);
        }
      }
      c3 = __fadd_rn(c3, b3v);
      m3 = leaky(m3, c3);
      s3 += (double)m3;
    }
    __syncthreads();
  }

  if (lane == 0) {
    double z = s3 / 25.0;
    out[s] = (float)(1.0 / (1.0 + exp(-z)));
  }
}

extern "C" void kernel_launch(void* const* d_in, const int* in_sizes, int n_in,
                              void* d_out, int out_size, void* d_ws, size_t ws_size,
                              hipStream_t stream) {
  const float* x  = (const float*)d_in[0];
  const float* W1 = (const float*)d_in[1];
  const float* b1 = (const float*)d_in[2];
  const float* W2 = (const float*)d_in[3];
  const float* b2 = (const float*)d_in[4];
  const float* W3 = (const float*)d_in[5];
  const float* b3 = (const float*)d_in[6];
  float* out = (float*)d_out;

  // Per-sample workspace: masks 25*32*4 = 3200 B, cur2 25*512*4 = 51200 B.
  const long long per_sample = 54400;
  long long smax = (d_ws != nullptr) ? (long long)(ws_size / per_sample) : 0;
  long long scap = smax > 65536 ? 65536 : smax;
  int S = (int)(scap & ~63LL);

  if (S >= 256) {
    u32* masks = (u32*)d_ws;
    float* cur2 = (float*)((char*)d_ws + (size_t)S * 3200);
    for (int s0 = 0; s0 < 65536; s0 += S) {
      int Sc = (65536 - s0 < S) ? (65536 - s0) : S;
      hipLaunchKernelGGL(k_spk1, dim3(Sc / 4), dim3(256), 0, stream,
                         x, W1, b1, masks, s0, Sc);
      hipLaunchKernelGGL(k_cur2, dim3((Sc * 25) / 64), dim3(256), 0, stream,
                         W2, b2, masks, cur2, Sc);
      hipLaunchKernelGGL(k_tail, dim3(Sc / 4), dim3(256), 0, stream,
                         cur2, W3, b3, out, s0, Sc);
    }
  } else {
    hipLaunchKernelGGL(k_snn, dim3(16384), dim3(256), 0, stream,
                       x, W1, b1, W2, b2, W3, b3, out);
  }
}